// Round 1
// baseline (471.535 us; speedup 1.0000x reference)
//
#include <hip/hip_runtime.h>

// ConvCaps: votes[b,h,w,ky,kx,i,o,m,n] = poses[b,h+ky,w+kx,i,m,n] * pk[ky,kx,i,o,m,n]
//           act_out[b,h,w,ky,kx,i]     = activations[b,h+ky,w+kx,i]
// Shapes: poses (4,16,16,32,4,4) f32, activations (4,16,16,32,1,1) f32,
//         pose_kernel (3,3,32,32,4,4) f32.  oh=ow=14 (VALID, stride 1).
// Output tuple concatenated flat: votes (115,605,504 f32) then act_out (225,792 f32).
// Memory-bound on the ~463 MB write stream; inputs (~2.6 MB) are L2-resident.

#define V4_COUNT 28901376   // votes float4s: 115605504 / 4
#define A4_COUNT 56448      // act float4s:   225792 / 4

__global__ __launch_bounds__(256) void convcaps_kernel(
    const float4* __restrict__ poses,   // (4,16,16,32, 16/4=4 float4)
    const float4* __restrict__ acts,    // (4,16,16, 32/4=8 float4)
    const float4* __restrict__ pk,      // (3,3,32,32, 4 float4)
    float4* __restrict__ out) {

    unsigned idx = blockIdx.x * 256u + threadIdx.x;

    if (idx < V4_COUNT) {
        // idx = ((((b*14+h)*14+w)*3+ky)*3+kx)*32i *32o *4e4  (e4 fastest)
        unsigned e4 = idx & 3u;
        unsigned o  = (idx >> 2) & 31u;
        unsigned i  = (idx >> 7) & 31u;
        unsigned r  = idx >> 12;          // (((b*14+h)*14+w)*3+ky)*3+kx
        unsigned kx = r % 3u;  r /= 3u;
        unsigned ky = r % 3u;  r /= 3u;
        unsigned w  = r % 14u; r /= 14u;
        unsigned h  = r % 14u; r /= 14u;
        unsigned b  = r;

        // poses float4 index: (((b*16 + h+ky)*16 + w+kx)*32 + i)*4 + e4
        float4 p = poses[(((b * 16u + h + ky) * 16u + (w + kx)) * 32u + i) * 4u + e4];
        // pose_kernel float4 index: (((ky*3+kx)*32 + i)*32 + o)*4 + e4
        float4 k = pk[(((ky * 3u + kx) * 32u + i) * 32u + o) * 4u + e4];

        float4 v;
        v.x = p.x * k.x;
        v.y = p.y * k.y;
        v.z = p.z * k.z;
        v.w = p.w * k.w;
        out[idx] = v;
    } else if (idx < V4_COUNT + A4_COUNT) {
        unsigned a  = idx - V4_COUNT;
        unsigned i4 = a & 7u;             // 8 float4s of 32 caps
        unsigned r  = a >> 3;
        unsigned kx = r % 3u;  r /= 3u;
        unsigned ky = r % 3u;  r /= 3u;
        unsigned w  = r % 14u; r /= 14u;
        unsigned h  = r % 14u; r /= 14u;
        unsigned b  = r;
        // activations float4 index: ((b*16 + h+ky)*16 + w+kx)*8 + i4
        out[idx] = acts[((b * 16u + h + ky) * 16u + (w + kx)) * 8u + i4];
    }
}

extern "C" void kernel_launch(void* const* d_in, const int* in_sizes, int n_in,
                              void* d_out, int out_size, void* d_ws, size_t ws_size,
                              hipStream_t stream) {
    const float4* poses = (const float4*)d_in[0];
    const float4* acts  = (const float4*)d_in[1];
    const float4* pk    = (const float4*)d_in[2];
    float4* out         = (float4*)d_out;

    const unsigned total = V4_COUNT + A4_COUNT;          // 28,957,824 float4s
    const unsigned blocks = (total + 255u) / 256u;        // 113,117
    convcaps_kernel<<<blocks, 256, 0, stream>>>(poses, acts, pk, out);
}